// Round 1
// baseline (1902.298 us; speedup 1.0000x reference)
//
#include <hip/hip_runtime.h>
#include <hip/hip_bf16.h>

// Problem dims (fixed): T=256, B=8, H=128, IN=256
#define T_LEN 256
#define BATCH 8
#define HID   128
#define SL    16   // h-slice per GRU workgroup

typedef _Float16 h2 __attribute__((ext_vector_type(2)));
typedef _Float16 h4 __attribute__((ext_vector_type(4)));

__device__ __forceinline__ float dot4(h4 w, h4 x, float acc) {
#if __has_builtin(__builtin_amdgcn_fdot2)
  h2 w0 = {w.x, w.y}, w1 = {w.z, w.w};
  h2 x0 = {x.x, x.y}, x1 = {x.z, x.w};
  acc = __builtin_amdgcn_fdot2(w0, x0, acc, false);
  acc = __builtin_amdgcn_fdot2(w1, x1, acc, false);
#else
  acc += (float)w.x*(float)x.x + (float)w.y*(float)x.y
       + (float)w.z*(float)x.z + (float)w.w*(float)x.w;
#endif
  return acc;
}

__device__ __forceinline__ float fsig(float x)  { return 1.f/(1.f+__expf(-x)); }
__device__ __forceinline__ float ftanhf(float x){ float e = __expf(2.f*x); return 1.f - 2.f/(e+1.f); }

__device__ __forceinline__ void wait_ge(unsigned* p, unsigned tgt) {
  while (__hip_atomic_load(p, __ATOMIC_RELAXED, __HIP_MEMORY_SCOPE_AGENT) < tgt)
    __builtin_amdgcn_s_sleep(1);
  __builtin_amdgcn_fence(__ATOMIC_ACQUIRE, "agent");
}

// ---------------- init: zero flags + h0 state ----------------
__global__ void k_init(unsigned* done, float* Hf32, _Float16* Hf16) {
  int n = blockIdx.x*blockDim.x + threadIdx.x;
  int NT = gridDim.x*blockDim.x;
  for (int k = n; k < 3*256; k += NT) done[k] = 0u;
  for (int k = n; k < 6*1024; k += NT) {            // slot 0 of each cell: 8*128
    int c = k >> 10, idx = k & 1023;
    Hf32[(size_t)c*257*1024 + idx] = 0.f;
    Hf16[(size_t)c*257*1024 + idx] = (_Float16)0.f;
  }
}

// ---------------- weight reformat (transposes + f16 packs) ----------------
__global__ void k_prep(const float* __restrict__ WvP, const float* __restrict__ WvPb,
                       const float* __restrict__ gatew,
                       const float* __restrict__ Wih, const float* __restrict__ Whh,
                       float* __restrict__ WvPT, float* __restrict__ WvPbT,
                       float* __restrict__ gwT, float* __restrict__ Wih0T,
                       h4* __restrict__ W4, h4* __restrict__ W04) {
  int n = blockIdx.x*blockDim.x + threadIdx.x;
  int NT = gridDim.x*blockDim.x;
  // WvPT/WvPbT: [256][128], src [128][256]
  for (int k = n; k < 256*128; k += NT) {
    int i = k >> 7, h = k & 127;
    WvPT[k]  = WvP[h*256 + i];
    WvPbT[k] = WvPb[h*256 + i];
  }
  // gate_wT: [256][256], src [e][d]
  for (int k = n; k < 256*256; k += NT) {
    int dd = k >> 8, e = k & 255;
    gwT[k] = gatew[e*256 + dd];
  }
  // Wih0T: [i=256][do=768] ; gru_Wih[0][d][o][i]
  for (int k = n; k < 256*768; k += NT) {
    int i = k / 768, doo = k % 768;
    Wih0T[k] = Wih[(size_t)doo*256 + i];
  }
  // W4: cells c=2..5 (layers 1,2): [cc][i4=96][o=384] h4, i<256 from Wih, else Whh
  for (int k = n; k < 4*96*384; k += NT) {
    int cc = k / (96*384), rem = k % (96*384);
    int i4 = rem / 384, o = rem % 384;
    int l = (cc + 2) >> 1, dd = (cc + 2) & 1;
    h4 w;
    #pragma unroll
    for (int e = 0; e < 4; ++e) {
      int i = 4*i4 + e;
      float v = (i < 256) ? Wih[(((size_t)(l*2+dd))*384 + o)*256 + i]
                          : Whh[(((size_t)(l*2+dd))*384 + o)*128 + (i-256)];
      w[e] = (_Float16)v;
    }
    W4[k] = w;
  }
  // W04: layer-0 cells: [d][j4=32][o=384] h4 from Whh[0][d]
  for (int k = n; k < 2*32*384; k += NT) {
    int dd = k / (32*384), rem = k % (32*384);
    int j4 = rem / 384, o = rem % 384;
    h4 w;
    #pragma unroll
    for (int e = 0; e < 4; ++e)
      w[e] = (_Float16)Whh[(((size_t)dd)*384 + o)*128 + 4*j4 + e];
    W04[k] = w;
  }
}

// ---------------- prep/pbar projections ----------------
// prepT[b][h][t] (coalesced-k reads later), pbar[t][b][h]
__global__ __launch_bounds__(256) void k_prep_pbar(
    const float* __restrict__ P, const float* __restrict__ WvPT,
    const float* __restrict__ WvPbT, float* __restrict__ prepT,
    float* __restrict__ pbar) {
  __shared__ float Pl[4*256];
  int R0 = blockIdx.x * 4, tid = threadIdx.x;
  for (int k = tid; k < 1024; k += 256) Pl[k] = P[(size_t)R0*256 + k];
  __syncthreads();
  int h = tid & 127;
  const float* Wt = (tid < 128) ? WvPT : WvPbT;
  float acc[4] = {0,0,0,0};
  for (int i = 0; i < 256; ++i) {
    float w = Wt[i*128 + h];
    acc[0] += Pl[i]*w; acc[1] += Pl[256+i]*w;
    acc[2] += Pl[512+i]*w; acc[3] += Pl[768+i]*w;
  }
  #pragma unroll
  for (int r = 0; r < 4; ++r) {
    int R = R0 + r, t = R >> 3, b = R & 7;
    if (tid < 128) prepT[((size_t)b*128 + h)*256 + t] = acc[r];
    else           pbar[(size_t)R*128 + h] = acc[r];
  }
}

// ---------------- fused attention + gate ----------------
__global__ __launch_bounds__(256) void k_attn(
    const float* __restrict__ prepT, const float* __restrict__ pbar,
    const float* __restrict__ vw, const float* __restrict__ gwT,
    float* __restrict__ ug) {
  int b = blockIdx.x & 7, q0 = (blockIdx.x >> 3) * 4;
  int tid = threadIdx.x;
  __shared__ float u[4][256];     // [j][d]: 0..127 pbar_q ; 128..255 ct
  __shared__ float vl[128];
  __shared__ float sc[4][256];
  __shared__ float red[4];
  if (tid < 128) vl[tid] = vw[tid];
  for (int k = tid; k < 512; k += 256) {
    int j = k >> 7, h = k & 127;
    u[j][h] = pbar[(((size_t)(q0+j))*8 + b)*128 + h];
  }
  __syncthreads();
  // scores: thread = k
  float s[4] = {0,0,0,0};
  for (int h = 0; h < 128; ++h) {
    float pk = prepT[((size_t)b*128 + h)*256 + tid];
    float vh = vl[h];
    #pragma unroll
    for (int j = 0; j < 4; ++j) {
      float e = __expf(2.f*(u[j][h] + pk));
      s[j] += vh * (1.f - 2.f/(e + 1.f));
    }
  }
  // softmax over k (256 threads)
  #pragma unroll
  for (int j = 0; j < 4; ++j) {
    float v = s[j];
    #pragma unroll
    for (int off = 32; off > 0; off >>= 1) v = fmaxf(v, __shfl_xor(v, off));
    if ((tid & 63) == 0) red[tid >> 6] = v;
    __syncthreads();
    float m = fmaxf(fmaxf(red[0], red[1]), fmaxf(red[2], red[3]));
    __syncthreads();
    float e = __expf(s[j] - m);
    v = e;
    #pragma unroll
    for (int off = 32; off > 0; off >>= 1) v += __shfl_xor(v, off);
    if ((tid & 63) == 0) red[tid >> 6] = v;
    __syncthreads();
    float sum = red[0] + red[1] + red[2] + red[3];
    __syncthreads();
    sc[j][tid] = e / sum;
  }
  __syncthreads();
  // ct[q][h] = sum_k a * pbar[k][b][h]
  {
    int h = tid & 127, jj = tid >> 7;
    float c0 = 0.f, c1 = 0.f;
    for (int k = 0; k < 256; ++k) {
      float p = pbar[((size_t)k*8 + b)*128 + h];
      c0 += sc[jj][k]   * p;
      c1 += sc[jj+2][k] * p;
    }
    u[jj][128+h]   = c0;
    u[jj+2][128+h] = c1;
  }
  __syncthreads();
  // gate: ug = u * sigmoid(u @ gate_w^T)
  {
    float gg[4] = {0,0,0,0};
    for (int dd = 0; dd < 256; ++dd) {
      float w = gwT[(size_t)dd*256 + tid];
      #pragma unroll
      for (int j = 0; j < 4; ++j) gg[j] += u[j][dd] * w;
    }
    #pragma unroll
    for (int j = 0; j < 4; ++j) {
      float ue = u[j][tid];
      ug[(((size_t)(q0+j))*8 + b)*256 + tid] = ue * fsig(gg[j]);
    }
  }
}

// ---------------- gi0 = ug @ Wih0^T + bih (layer 0, both dirs) ----------------
__global__ __launch_bounds__(256) void k_gi0(
    const float* __restrict__ ug, const float* __restrict__ Wih0T,
    const float* __restrict__ bih, float* __restrict__ gi0) {
  __shared__ float ul[8][256];
  int R0 = blockIdx.x * 8, tid = threadIdx.x;
  for (int k = tid; k < 2048; k += 256) ul[k >> 8][k & 255] = ug[(size_t)R0*256 + k];
  __syncthreads();
  float acc[3][8];
  #pragma unroll
  for (int a = 0; a < 3; ++a)
    #pragma unroll
    for (int r = 0; r < 8; ++r) acc[a][r] = 0.f;
  for (int i = 0; i < 256; ++i) {
    float w0 = Wih0T[(size_t)i*768 + tid];
    float w1 = Wih0T[(size_t)i*768 + 256 + tid];
    float w2 = Wih0T[(size_t)i*768 + 512 + tid];
    #pragma unroll
    for (int r = 0; r < 8; ++r) {
      float uu = ul[r][i];
      acc[0][r] += uu*w0; acc[1][r] += uu*w1; acc[2][r] += uu*w2;
    }
  }
  float b0 = bih[tid], b1 = bih[256 + tid], b2 = bih[512 + tid];
  #pragma unroll
  for (int r = 0; r < 8; ++r) {
    gi0[((size_t)(R0+r))*768 + tid]       = acc[0][r] + b0;
    gi0[((size_t)(R0+r))*768 + 256 + tid] = acc[1][r] + b1;
    gi0[((size_t)(R0+r))*768 + 512 + tid] = acc[2][r] + b2;
  }
}

// ---------------- persistent pipelined GRU ----------------
// 48 WGs: wg -> cell c = wg>>3 (l=c>>1, d=c&1), slice sl = wg&7, h0 = 16*sl.
// Weight slice (f16) LDS-resident; diagonal pipeline via done[l][t] flags (target 16).
__global__ __launch_bounds__(256, 1) void k_gru(
    const h4* __restrict__ W4, const h4* __restrict__ W04,
    const float* __restrict__ gi0,
    const float* __restrict__ bih, const float* __restrict__ bhh,
    float* __restrict__ Hf32, _Float16* Hf16s,
    float* __restrict__ out, unsigned* done) {
  const h4* Hf16 = (const h4*)Hf16s;
  const int wg = blockIdx.x;
  const int c = wg >> 3, sl = wg & 7;
  const int l = c >> 1, d = c & 1;
  const int h0 = sl * SL;
  const int tid = threadIdx.x;

  __shared__ h4 Wlds[96*48];        // 36.9 KB
  __shared__ h4 x4[64][8];          // layer input (i4, b)
  __shared__ h4 hh4[32][8];         // own h (j4, b)
  __shared__ float accx[48][8];
  __shared__ float acch[48][8];

  { // preload weight slice into LDS (once)
    const h4* Wsrc = (l == 0) ? (W04 + (size_t)d*32*384) : (W4 + (size_t)(c-2)*96*384);
    const int NW = (l == 0) ? 32*48 : 96*48;
    for (int k = tid; k < NW; k += 256) {
      int i4 = k / 48, ol = k % 48;
      int o = (ol/SL)*128 + h0 + (ol%SL);
      Wlds[k] = Wsrc[(size_t)i4*384 + o];
    }
  }

  const bool mv = (tid < 192);
  const int o_l = tid % 48;
  const int bh  = tid / 48;                 // 0..3 (mv threads)
  const int g   = o_l / SL;
  const int o   = g*128 + h0 + (o_l % SL);  // column 0..383 (gate-major r,z,n)
  float b_i = 0.f, b_h = 0.f;
  if (mv) {
    b_i = bih[(size_t)(l*2+d)*384 + o];
    b_h = bhh[(size_t)(l*2+d)*384 + o];
  }
  const int cinf = (l > 0) ? (l-1)*2 : 0, cinb = cinf + 1;
  unsigned* dn_own = done + l*256;
  unsigned* dn_in  = done + (l > 0 ? (l-1)*256 : 0);

  __syncthreads();

  for (int t = 0; t < T_LEN; ++t) {
    if (t > 0) wait_ge(&dn_own[t-1], 16);
    if (l > 0) wait_ge(&dn_in[t], 16);
    if (l > 0) {  // stage x = concat(hf, hb) of layer l-1 at time t (slot t+1)
      for (int k = tid; k < 512; k += 256) {
        int i4 = k >> 3, b = k & 7;
        int cc = (i4 < 32) ? cinf : cinb;
        int ii = i4 & 31;
        x4[i4][b] = Hf16[(((size_t)cc*257 + (t+1))*8 + b)*32 + ii];
      }
    }
    { // stage own h(t-1) (slot t)
      int i4 = tid >> 3, b = tid & 7;
      hh4[i4][b] = Hf16[(((size_t)c*257 + t)*8 + b)*32 + i4];
    }
    __syncthreads();

    if (mv) {
      float a1[2], a2[2];
      if (l == 0) {
        #pragma unroll
        for (int j = 0; j < 2; ++j) {
          int b = 2*bh + j;
          a1[j] = gi0[((size_t)t*8 + b)*768 + d*384 + o] + (g < 2 ? b_h : 0.f);
          a2[j] = (g == 2) ? b_h : 0.f;
        }
      } else {
        a1[0] = a1[1] = (g < 2) ? (b_i + b_h) : b_i;
        a2[0] = a2[1] = (g == 2) ? b_h : 0.f;
        #pragma unroll 8
        for (int i4 = 0; i4 < 64; ++i4) {
          h4 w = Wlds[i4*48 + o_l];
          a1[0] = dot4(w, x4[i4][2*bh],   a1[0]);
          a1[1] = dot4(w, x4[i4][2*bh+1], a1[1]);
        }
      }
      const int wbase = (l == 0) ? 0 : 64*48;
      #pragma unroll 8
      for (int j4 = 0; j4 < 32; ++j4) {
        h4 w = Wlds[wbase + j4*48 + o_l];
        a2[0] = dot4(w, hh4[j4][2*bh],   a2[0]);
        a2[1] = dot4(w, hh4[j4][2*bh+1], a2[1]);
      }
      accx[o_l][2*bh]   = a1[0];
      accx[o_l][2*bh+1] = a1[1];
      acch[o_l][2*bh]   = a2[0];
      acch[o_l][2*bh+1] = a2[1];
    }
    __syncthreads();

    if (tid < 128) {  // combine gates, update state
      int hl = tid >> 3, b = tid & 7;
      float r = fsig(accx[hl][b] + acch[hl][b]);
      float z = fsig(accx[SL+hl][b] + acch[SL+hl][b]);
      float n = ftanhf(accx[2*SL+hl][b] + r*acch[2*SL+hl][b]);
      float hp = Hf32[(((size_t)c*257 + t)*8 + b)*128 + h0 + hl];
      float hn = (1.f - z)*n + z*hp;
      Hf32[(((size_t)c*257 + t+1)*8 + b)*128 + h0 + hl] = hn;
      Hf16s[(((size_t)c*257 + t+1)*8 + b)*128 + h0 + hl] = (_Float16)hn;
      if (l == 2) out[((size_t)b*256 + t)*256 + d*128 + h0 + hl] = hn;
    }
    __syncthreads();
    if (tid == 0)
      __hip_atomic_fetch_add(&dn_own[t], 1u, __ATOMIC_RELEASE, __HIP_MEMORY_SCOPE_AGENT);
  }
}

extern "C" void kernel_launch(void* const* d_in, const int* in_sizes, int n_in,
                              void* d_out, int out_size, void* d_ws, size_t ws_size,
                              hipStream_t stream) {
  (void)in_sizes; (void)n_in; (void)out_size; (void)ws_size;
  const float* P     = (const float*)d_in[0];
  const float* vw    = (const float*)d_in[2];
  const float* WvP   = (const float*)d_in[3];
  const float* WvPb  = (const float*)d_in[4];
  const float* gatew = (const float*)d_in[5];
  const float* Wih   = (const float*)d_in[6];
  const float* Whh   = (const float*)d_in[7];
  const float* bih   = (const float*)d_in[8];
  const float* bhh   = (const float*)d_in[9];
  float* out = (float*)d_out;

  char* wsp = (char*)d_ws;
  size_t off = 0;
  auto alloc = [&](size_t nbytes) -> void* {
    void* p = wsp + off;
    off += (nbytes + 255) & ~(size_t)255;
    return p;
  };
  float*    prepT = (float*)   alloc((size_t)8*128*256*4);   // [b][h][t]
  float*    pbar  = (float*)   alloc((size_t)256*8*128*4);   // [t][b][h]
  float*    ug    = (float*)   alloc((size_t)256*8*256*4);   // gated u
  float*    gi0   = (float*)   alloc((size_t)2048*768*4);    // layer0 gi
  float*    Hf32  = (float*)   alloc((size_t)6*257*8*128*4);
  _Float16* Hf16  = (_Float16*)alloc((size_t)6*257*8*128*2);
  h4*       W4    = (h4*)      alloc((size_t)4*96*384*8);
  h4*       W04   = (h4*)      alloc((size_t)2*32*384*8);
  float*    WvPT  = (float*)   alloc((size_t)256*128*4);
  float*    WvPbT = (float*)   alloc((size_t)256*128*4);
  float*    gwT   = (float*)   alloc((size_t)256*256*4);
  float*    Wih0T = (float*)   alloc((size_t)256*768*4);
  unsigned* done  = (unsigned*)alloc((size_t)3*256*4);

  hipLaunchKernelGGL(k_init, dim3(8), dim3(256), 0, stream, done, Hf32, Hf16);
  hipLaunchKernelGGL(k_prep, dim3(256), dim3(256), 0, stream,
                     WvP, WvPb, gatew, Wih, Whh, WvPT, WvPbT, gwT, Wih0T, W4, W04);
  hipLaunchKernelGGL(k_prep_pbar, dim3(512), dim3(256), 0, stream,
                     P, WvPT, WvPbT, prepT, pbar);
  hipLaunchKernelGGL(k_attn, dim3(512), dim3(256), 0, stream,
                     prepT, pbar, vw, gwT, ug);
  hipLaunchKernelGGL(k_gi0, dim3(256), dim3(256), 0, stream,
                     ug, Wih0T, bih, gi0);
  hipLaunchKernelGGL(k_gru, dim3(48), dim3(256), 0, stream,
                     W4, W04, gi0, bih, bhh, Hf32, Hf16, out, done);
}

// Round 3
// 661.301 us; speedup vs baseline: 2.8766x; 2.8766x over previous
//
#include <hip/hip_runtime.h>
#include <hip/hip_bf16.h>

// Problem dims (fixed): T=256, B=8, H=128, IN=256
#define T_LEN 256

typedef _Float16 f16x8 __attribute__((ext_vector_type(8)));
typedef float f32x4 __attribute__((ext_vector_type(4)));

__device__ __forceinline__ float fsig(float x)  { return 1.f/(1.f+__expf(-x)); }
__device__ __forceinline__ float ftanhf(float x){ float e = __expf(2.f*x); return 1.f - 2.f/(e+1.f); }

#define MFMA16(a,b,c) __builtin_amdgcn_mfma_f32_16x16x32_f16(a, b, c, 0, 0, 0)

// ---------------- init: zero flags ----------------
__global__ void k_init(unsigned* flags) {
  int n = threadIdx.x;
  if (n < 6*16) flags[n] = 0u;
}

// ---------------- weight reformat ----------------
// WvPT/WvPbT: [256][128]; gwT: [256][256]; Wih0T: [i=256][o=768]
// Wh: f16 [c=6][o=384][k=128]  (Whh row-major)
// Wx: f16 [cc=4][o=384][k=256] (Wih row-major, cells 2..5)
__global__ void k_prep(const float* __restrict__ WvP, const float* __restrict__ WvPb,
                       const float* __restrict__ gatew,
                       const float* __restrict__ Wih, const float* __restrict__ Whh,
                       float* __restrict__ WvPT, float* __restrict__ WvPbT,
                       float* __restrict__ gwT, float* __restrict__ Wih0T,
                       _Float16* __restrict__ Wx, _Float16* __restrict__ Wh) {
  int n = blockIdx.x*blockDim.x + threadIdx.x;
  int NT = gridDim.x*blockDim.x;
  for (int k = n; k < 256*128; k += NT) {
    int i = k >> 7, h = k & 127;
    WvPT[k]  = WvP[h*256 + i];
    WvPbT[k] = WvPb[h*256 + i];
  }
  for (int k = n; k < 256*256; k += NT) {
    int dd = k >> 8, e = k & 255;
    gwT[k] = gatew[e*256 + dd];
  }
  for (int k = n; k < 256*768; k += NT) {
    int i = k / 768, doo = k % 768;
    Wih0T[k] = Wih[(size_t)doo*256 + i];
  }
  for (int k = n; k < 6*384*128; k += NT) {
    Wh[k] = (_Float16)Whh[k];           // identical flat layout [c][o][128]
  }
  for (int k = n; k < 4*384*256; k += NT) {
    Wx[k] = (_Float16)Wih[(size_t)2*384*256 + k];  // cells 2..5 = Wih rows 2..5
  }
}

// ---------------- prep/pbar projections ----------------
__global__ __launch_bounds__(256) void k_prep_pbar(
    const float* __restrict__ P, const float* __restrict__ WvPT,
    const float* __restrict__ WvPbT, float* __restrict__ prepT,
    float* __restrict__ pbar) {
  __shared__ float Pl[4*256];
  int R0 = blockIdx.x * 4, tid = threadIdx.x;
  for (int k = tid; k < 1024; k += 256) Pl[k] = P[(size_t)R0*256 + k];
  __syncthreads();
  int h = tid & 127;
  const float* Wt = (tid < 128) ? WvPT : WvPbT;
  float acc[4] = {0,0,0,0};
  for (int i = 0; i < 256; ++i) {
    float w = Wt[i*128 + h];
    acc[0] += Pl[i]*w; acc[1] += Pl[256+i]*w;
    acc[2] += Pl[512+i]*w; acc[3] += Pl[768+i]*w;
  }
  #pragma unroll
  for (int r = 0; r < 4; ++r) {
    int R = R0 + r, t = R >> 3, b = R & 7;
    if (tid < 128) prepT[((size_t)b*128 + h)*256 + t] = acc[r];
    else           pbar[(size_t)R*128 + h] = acc[r];
  }
}

// ---------------- fused attention + gate ----------------
__global__ __launch_bounds__(256) void k_attn(
    const float* __restrict__ prepT, const float* __restrict__ pbar,
    const float* __restrict__ vw, const float* __restrict__ gwT,
    float* __restrict__ ug) {
  int b = blockIdx.x & 7, q0 = (blockIdx.x >> 3) * 4;
  int tid = threadIdx.x;
  __shared__ float u[4][256];
  __shared__ float vl[128];
  __shared__ float sc[4][256];
  __shared__ float red[4];
  if (tid < 128) vl[tid] = vw[tid];
  for (int k = tid; k < 512; k += 256) {
    int j = k >> 7, h = k & 127;
    u[j][h] = pbar[(((size_t)(q0+j))*8 + b)*128 + h];
  }
  __syncthreads();
  float s[4] = {0,0,0,0};
  for (int h = 0; h < 128; ++h) {
    float pk = prepT[((size_t)b*128 + h)*256 + tid];
    float vh = vl[h];
    #pragma unroll
    for (int j = 0; j < 4; ++j) {
      float e = __expf(2.f*(u[j][h] + pk));
      s[j] += vh * (1.f - 2.f/(e + 1.f));
    }
  }
  #pragma unroll
  for (int j = 0; j < 4; ++j) {
    float v = s[j];
    #pragma unroll
    for (int off = 32; off > 0; off >>= 1) v = fmaxf(v, __shfl_xor(v, off));
    if ((tid & 63) == 0) red[tid >> 6] = v;
    __syncthreads();
    float m = fmaxf(fmaxf(red[0], red[1]), fmaxf(red[2], red[3]));
    __syncthreads();
    float e = __expf(s[j] - m);
    v = e;
    #pragma unroll
    for (int off = 32; off > 0; off >>= 1) v += __shfl_xor(v, off);
    if ((tid & 63) == 0) red[tid >> 6] = v;
    __syncthreads();
    float sum = red[0] + red[1] + red[2] + red[3];
    __syncthreads();
    sc[j][tid] = e / sum;
  }
  __syncthreads();
  {
    int h = tid & 127, jj = tid >> 7;
    float c0 = 0.f, c1 = 0.f;
    for (int k = 0; k < 256; ++k) {
      float p = pbar[((size_t)k*8 + b)*128 + h];
      c0 += sc[jj][k]   * p;
      c1 += sc[jj+2][k] * p;
    }
    u[jj][128+h]   = c0;
    u[jj+2][128+h] = c1;
  }
  __syncthreads();
  {
    float gg[4] = {0,0,0,0};
    for (int dd = 0; dd < 256; ++dd) {
      float w = gwT[(size_t)dd*256 + tid];
      #pragma unroll
      for (int j = 0; j < 4; ++j) gg[j] += u[j][dd] * w;
    }
    #pragma unroll
    for (int j = 0; j < 4; ++j) {
      float ue = u[j][tid];
      ug[(((size_t)(q0+j))*8 + b)*256 + tid] = ue * fsig(gg[j]);
    }
  }
}

// ---------------- gi0 = ug @ Wih0^T + bih : output [t][o=768][b=8] ----------------
__global__ __launch_bounds__(256) void k_gi0(
    const float* __restrict__ ug, const float* __restrict__ Wih0T,
    const float* __restrict__ bih, float* __restrict__ gi0) {
  __shared__ float ul[8][256];
  __shared__ float st[768*8];
  int t = blockIdx.x, tid = threadIdx.x;
  for (int k = tid; k < 2048; k += 256) ul[k >> 8][k & 255] = ug[(size_t)t*2048 + k];
  __syncthreads();
  float acc[3][8];
  #pragma unroll
  for (int a = 0; a < 3; ++a)
    #pragma unroll
    for (int r = 0; r < 8; ++r) acc[a][r] = 0.f;
  for (int i = 0; i < 256; ++i) {
    float w0 = Wih0T[(size_t)i*768 + tid];
    float w1 = Wih0T[(size_t)i*768 + 256 + tid];
    float w2 = Wih0T[(size_t)i*768 + 512 + tid];
    #pragma unroll
    for (int r = 0; r < 8; ++r) {
      float uu = ul[r][i];
      acc[0][r] += uu*w0; acc[1][r] += uu*w1; acc[2][r] += uu*w2;
    }
  }
  float b0 = bih[tid], b1 = bih[256 + tid], b2 = bih[512 + tid];
  #pragma unroll
  for (int a = 0; a < 3; ++a) {
    int o = a*256 + tid;
    float ba = (a == 0) ? b0 : (a == 1) ? b1 : b2;
    #pragma unroll
    for (int r = 0; r < 8; ++r) st[o*8 + r] = acc[a][r] + ba;
  }
  __syncthreads();
  #pragma unroll
  for (int j = 0; j < 6; ++j) {
    int idx = j*256 + tid;            // 1536 float4 chunks
    ((f32x4*)gi0)[(size_t)t*1536 + idx] = ((const f32x4*)st)[idx];
  }
}

// ---------------- persistent GRU: one cell per WG, MFMA, L3 pipeline handoff ----
// 6 WGs x 512 threads. Cell c: l=c>>1, d=c&1.
// X LDS tile [16 rows(batch)][384 cols] f16, row stride 768B, XOR-swizzled.
//   cols 0..255 = x input (l>0), cols HOFF.. = own h(t-1). l==0: HOFF=0, h at 0..127.
// Weights register-resident as MFMA B-frags. Handoff: Hbuf[c][t][b][32 ull] f16 via
// agent-scope atomics + per-cell monotonic flag counter (release store).
__global__ __launch_bounds__(512, 2) void k_gru2(
    const _Float16* __restrict__ Wx, const _Float16* __restrict__ Wh,
    const float* __restrict__ gi0, const float* __restrict__ bih,
    const float* __restrict__ bhh, unsigned long long* Hbuf,
    float* __restrict__ out, unsigned* flags)
{
  const int c = blockIdx.x, l = c >> 1, d = c & 1;
  const int tid = threadIdx.x;
  const int w = tid >> 6, lane = tid & 63;
  const int lo = lane & 15, hi = lane >> 4;
  const int HOFF = (l == 0) ? 0 : 256;

  __shared__ _Float16 X[16 * 384];    // 12 KiB

  { // zero X (rows 8..15 stay zero forever -> no NaN in unused D rows)
    f16x8 z = {0,0,0,0,0,0,0,0};
    for (int p = tid; p < 768; p += 512) ((f16x8*)X)[p] = z;
  }

  // ---- B-fragments (weights) into registers ----
  f16x8 bh[3][4];
  #pragma unroll
  for (int nt = 0; nt < 3; ++nt) {
    int o = 16 * (w + 8*nt) + lo;
    #pragma unroll
    for (int ks = 0; ks < 4; ++ks)
      bh[nt][ks] = *(const f16x8*)(Wh + ((size_t)c*384 + o)*128 + 32*ks + 8*hi);
  }
  f16x8 bx[3][8];
  if (l > 0) {
    #pragma unroll
    for (int nt = 0; nt < 3; ++nt) {
      int o = 16 * (w + 8*nt) + lo;
      #pragma unroll
      for (int ks = 0; ks < 8; ++ks)
        bx[nt][ks] = *(const f16x8*)(Wx + ((size_t)(c-2)*384 + o)*256 + 32*ks + 8*hi);
    }
  }

  // ---- per-lane biases (h index = 16w + lo; gates r,z,n) ----
  const int hidx = 16*w + lo;
  float b_r, b_z, b_in, b_hn;
  {
    const size_t bb = (size_t)c * 384;
    float bir = bih[bb + hidx], biz = bih[bb + 128 + hidx], bin = bih[bb + 256 + hidx];
    float bhr = bhh[bb + hidx], bhz = bhh[bb + 128 + hidx], bhn = bhh[bb + 256 + hidx];
    if (l == 0) { b_r = bhr; b_z = bhz; b_in = 0.f;  b_hn = bhn; }
    else        { b_r = bir + bhr; b_z = biz + bhz; b_in = bin; b_hn = bhn; }
  }

  // ---- staging setup (consumers: l>0, threads 0..255) ----
  // Hbuf layout: [c][t][b][32 ull]  (32 ull = 128 f16 = one h vector)
  const int cinf = (l - 1) * 2;
  const bool stg = (l > 0) && (tid < 256);
  const int sb = tid >> 5, sp = tid & 31;
  const int scell = (sp < 16) ? cinf : (cinf + 1);
  const size_t sbase = (((size_t)scell * 256) * 8 + sb) * 32 + 2 * (sp & 15);
  unsigned* sflag = flags + scell * 16;

  unsigned Vready = 0;
  float hp[4] = {0,0,0,0};
  __syncthreads();

  for (int t = 0; t < T_LEN; ++t) {
    // -- A: poll producer + issue x loads (L3-direct atomics) --
    unsigned long long xv0 = 0, xv1 = 0;
    if (stg) {
      if (Vready < (unsigned)(t + 1)) {
        do {
          Vready = __hip_atomic_load(sflag, __ATOMIC_RELAXED, __HIP_MEMORY_SCOPE_AGENT);
          if (Vready < (unsigned)(t + 1)) __builtin_amdgcn_s_sleep(2);
        } while (Vready < (unsigned)(t + 1));
        __builtin_amdgcn_fence(__ATOMIC_ACQUIRE, "agent");
      }
      size_t idx = sbase + (size_t)t * 256;     // t stride = 8 b * 32 ull
      xv0 = __hip_atomic_load(Hbuf + idx,     __ATOMIC_RELAXED, __HIP_MEMORY_SCOPE_AGENT);
      xv1 = __hip_atomic_load(Hbuf + idx + 1, __ATOMIC_RELAXED, __HIP_MEMORY_SCOPE_AGENT);
    }
    // -- B: layer-0 gi loads (precomputed x-part, f32) --
    f32x4 gx0, gx1, gx2;
    if (l == 0) {
      const float* g = gi0 + ((size_t)t*768 + (size_t)d*384) * 8;
      int b0 = 4 * (hi & 1);
      gx0 = *(const f32x4*)(g + (size_t)hidx*8 + b0);
      gx1 = *(const f32x4*)(g + ((size_t)128 + hidx)*8 + b0);
      gx2 = *(const f32x4*)(g + ((size_t)256 + hidx)*8 + b0);
    }
    // -- C: h-part MFMAs (reads h(t-1) from X) --
    f32x4 ah0 = {0,0,0,0}, ah1 = {0,0,0,0}, ah2 = {0,0,0,0};
    {
      f16x8 a[4];
      #pragma unroll
      for (int ks = 0; ks < 4; ++ks) {
        int byte = lo*768 + (HOFF + 32*ks + 8*hi)*2; byte ^= (lo & 7) << 4;
        a[ks] = *(const f16x8*)((const char*)X + byte);
      }
      #pragma unroll
      for (int ks = 0; ks < 4; ++ks) {
        ah0 = MFMA16(a[ks], bh[0][ks], ah0);
        ah1 = MFMA16(a[ks], bh[1][ks], ah1);
        ah2 = MFMA16(a[ks], bh[2][ks], ah2);
      }
    }
    // -- D: write staged x into X --
    if (stg) {
      asm volatile("s_waitcnt vmcnt(0)");
      int byte = sb*768 + (8*sp)*2; byte ^= (sb & 7) << 4;
      unsigned long long* dst = (unsigned long long*)((char*)X + byte);
      dst[0] = xv0; dst[1] = xv1;
    }
    __syncthreads();
    // -- F: x-part MFMAs (l>0) --
    f32x4 ax0, ax1, ax2;
    if (l > 0) {
      ax0 = (f32x4){0,0,0,0}; ax1 = (f32x4){0,0,0,0}; ax2 = (f32x4){0,0,0,0};
      f16x8 a[8];
      #pragma unroll
      for (int ks = 0; ks < 8; ++ks) {
        int byte = lo*768 + (32*ks + 8*hi)*2; byte ^= (lo & 7) << 4;
        a[ks] = *(const f16x8*)((const char*)X + byte);
      }
      #pragma unroll
      for (int ks = 0; ks < 8; ++ks) {
        ax0 = MFMA16(a[ks], bx[0][ks], ax0);
        ax1 = MFMA16(a[ks], bx[1][ks], ax1);
        ax2 = MFMA16(a[ks], bx[2][ks], ax2);
      }
    } else {
      ax0 = gx0; ax1 = gx1; ax2 = gx2;
    }
    // -- G: combine gates + state update (valid lanes: lane<32 -> b=4*hi+q) --
    float hn[4];
    #pragma unroll
    for (int q = 0; q < 4; ++q) {
      float r  = fsig(ax0[q] + ah0[q] + b_r);
      float z  = fsig(ax1[q] + ah1[q] + b_z);
      float nn = ftanhf(ax2[q] + b_in + r * (ah2[q] + b_hn));
      hn[q] = (1.f - z) * nn + z * hp[q];
      hp[q] = hn[q];
    }
    // -- H: write h(t) into X (f16) + out (l==2, f32) --
    if (lane < 32) {
      #pragma unroll
      for (int q = 0; q < 4; ++q) {
        int b = 4*hi + q;
        int byte = b*768 + (HOFF + hidx)*2; byte ^= (b & 7) << 4;
        *(_Float16*)((char*)X + byte) = (_Float16)hn[q];
        if (l == 2) out[((size_t)b*256 + t)*256 + d*128 + hidx] = hn[q];
      }
    }
    __syncthreads();
    // -- J: publish h(t) to L3 + flag (producers: l<2) --
    if (l < 2) {
      if (tid < 128) {
        int b = tid >> 4, p = tid & 15;
        int byte = b*768 + (HOFF + 8*p)*2; byte ^= (b & 7) << 4;
        const unsigned long long* src = (const unsigned long long*)((const char*)X + byte);
        size_t idx = (((size_t)c*256 + t) * 8 + b) * 32 + 2*p;
        unsigned long long v0 = src[0], v1 = src[1];
        __hip_atomic_store(Hbuf + idx,     v0, __ATOMIC_RELAXED, __HIP_MEMORY_SCOPE_AGENT);
        __hip_atomic_store(Hbuf + idx + 1, v1, __ATOMIC_RELAXED, __HIP_MEMORY_SCOPE_AGENT);
      }
      __syncthreads();
      if (tid == 0)
        __hip_atomic_store(flags + c*16, (unsigned)(t + 1),
                           __ATOMIC_RELEASE, __HIP_MEMORY_SCOPE_AGENT);
    }
  }
}

extern "C" void kernel_launch(void* const* d_in, const int* in_sizes, int n_in,
                              void* d_out, int out_size, void* d_ws, size_t ws_size,
                              hipStream_t stream) {
  (void)in_sizes; (void)n_in; (void)out_size; (void)ws_size;
  const float* P     = (const float*)d_in[0];
  const float* vw    = (const float*)d_in[2];
  const float* WvP   = (const float*)d_in[3];
  const float* WvPb  = (const float*)d_in[4];
  const float* gatew = (const float*)d_in[5];
  const float* Wih   = (const float*)d_in[6];
  const float* Whh   = (const float*)d_in[7];
  const float* bih   = (const float*)d_in[8];
  const float* bhh   = (const float*)d_in[9];
  float* out = (float*)d_out;

  char* wsp = (char*)d_ws;
  size_t off = 0;
  auto alloc = [&](size_t nbytes) -> void* {
    void* p = wsp + off;
    off += (nbytes + 255) & ~(size_t)255;
    return p;
  };
  float*    prepT = (float*)   alloc((size_t)8*128*256*4);
  float*    pbar  = (float*)   alloc((size_t)256*8*128*4);
  float*    ug    = (float*)   alloc((size_t)256*8*256*4);
  float*    gi0   = (float*)   alloc((size_t)256*768*8*4);     // [t][o][b]
  unsigned long long* Hbuf = (unsigned long long*)alloc((size_t)4*256*8*32*8);  // [c][t][b][32 ull]
  _Float16* Wx    = (_Float16*)alloc((size_t)4*384*256*2);
  _Float16* Wh    = (_Float16*)alloc((size_t)6*384*128*2);
  float*    WvPT  = (float*)   alloc((size_t)256*128*4);
  float*    WvPbT = (float*)   alloc((size_t)256*128*4);
  float*    gwT   = (float*)   alloc((size_t)256*256*4);
  float*    Wih0T = (float*)   alloc((size_t)256*768*4);
  unsigned* flags = (unsigned*)alloc((size_t)6*16*4);

  hipLaunchKernelGGL(k_init, dim3(1), dim3(128), 0, stream, flags);
  hipLaunchKernelGGL(k_prep, dim3(256), dim3(256), 0, stream,
                     WvP, WvPb, gatew, Wih, Whh, WvPT, WvPbT, gwT, Wih0T, Wx, Wh);
  hipLaunchKernelGGL(k_prep_pbar, dim3(512), dim3(256), 0, stream,
                     P, WvPT, WvPbT, prepT, pbar);
  hipLaunchKernelGGL(k_attn, dim3(512), dim3(256), 0, stream,
                     prepT, pbar, vw, gwT, ug);
  hipLaunchKernelGGL(k_gi0, dim3(256), dim3(256), 0, stream,
                     ug, Wih0T, bih, gi0);
  hipLaunchKernelGGL(k_gru2, dim3(6), dim3(512), 0, stream,
                     Wx, Wh, gi0, bih, bhh, Hbuf, out, flags);
}